// Round 1
// baseline (241.021 us; speedup 1.0000x reference)
//
#include <hip/hip_runtime.h>
#include <hip/hip_bf16.h>

#define HEADS 12
#define HD    64
#define SEQ   2048
#define CDIM  768
#define QKV_SCALE 0.03608439182435161f  // 768^-0.5 (module scales by full dim)

typedef __attribute__((ext_vector_type(8))) short bf16x8;
typedef __attribute__((ext_vector_type(4))) float f32x4;
typedef __attribute__((ext_vector_type(4))) unsigned short usx4;
typedef __attribute__((ext_vector_type(8))) unsigned short usx8;

__device__ __forceinline__ unsigned short f2bf(float f) {
  union { __hip_bfloat16 h; unsigned short u; } c;
  c.h = __float2bfloat16(f);
  return c.u;
}

__device__ __forceinline__ void gload_lds16(const unsigned short* g, unsigned short* l) {
  __builtin_amdgcn_global_load_lds(
      (__attribute__((address_space(1))) void*)(g),
      (__attribute__((address_space(3))) void*)(l), 16, 0, 0);
}

// ---------------- convert x (fp32 -> bf16), 8 elems/thread ----------------
__global__ __launch_bounds__(256) void k_cvt_x(const float* __restrict__ src,
                                               unsigned short* __restrict__ dst) {
  int i = blockIdx.x * 256 + threadIdx.x;  // grid sized exactly: 786432 threads
  const float4* s4 = (const float4*)src;
  float4 a = s4[i * 2 + 0];
  float4 b = s4[i * 2 + 1];
  usx8 r;
  r[0] = f2bf(a.x); r[1] = f2bf(a.y); r[2] = f2bf(a.z); r[3] = f2bf(a.w);
  r[4] = f2bf(b.x); r[5] = f2bf(b.y); r[6] = f2bf(b.z); r[7] = f2bf(b.w);
  *(usx8*)&dst[i * 8] = r;
}

// ---------------- transpose fp32 [K][C] -> bf16 [C][K] ----------------
__global__ __launch_bounds__(256) void k_transpose(const float* __restrict__ src,
                                                   unsigned short* __restrict__ dst,
                                                   int K, int C) {
  __shared__ float tile[32][33];
  int tx = threadIdx.x & 31;
  int ty = threadIdx.x >> 5;
  int c0 = blockIdx.x * 32;
  int k0 = blockIdx.y * 32;
#pragma unroll
  for (int i = 0; i < 32; i += 8)
    tile[ty + i][tx] = src[(size_t)(k0 + ty + i) * C + c0 + tx];
  __syncthreads();
#pragma unroll
  for (int i = 0; i < 32; i += 8)
    dst[(size_t)(c0 + ty + i) * K + k0 + tx] = f2bf(tile[tx][ty + i]);
}

// ---------------- qkv GEMM: [8192x768]bf16 @ [768x2304] -> scatter Q,K,V^T ----------------
__global__ __launch_bounds__(256) void k_qkv_gemm(
    const unsigned short* __restrict__ A,   // xb [8192][768]
    const unsigned short* __restrict__ Bt,  // WqkvT [2304][768]
    unsigned short* __restrict__ Qb, unsigned short* __restrict__ Kb,
    unsigned short* __restrict__ Vt) {
  __shared__ unsigned short As[128 * 64];
  __shared__ unsigned short Bs[128 * 64];
  const int lane = threadIdx.x & 63, w = threadIdx.x >> 6;
  const int wm = w >> 1, wn = w & 1;
  const int r0 = blockIdx.y * 128, c0 = blockIdx.x * 128;
  f32x4 acc[4][4] = {};

  for (int k0 = 0; k0 < 768; k0 += 64) {
#pragma unroll
    for (int iss = 0; iss < 4; ++iss) {
      int eo = (w * 4 + iss) * 512 + lane * 8;
      int row = eo >> 6;
      int cc = ((eo >> 3) & 7) ^ (row & 7);  // pre-swizzled source -> swizzled LDS
      gload_lds16(A + (size_t)(r0 + row) * 768 + k0 + cc * 8, &As[(w * 4 + iss) * 512]);
    }
#pragma unroll
    for (int iss = 0; iss < 4; ++iss) {
      int eo = (w * 4 + iss) * 512 + lane * 8;
      int row = eo >> 6;
      int cc = ((eo >> 3) & 7) ^ (row & 7);
      gload_lds16(Bt + (size_t)(c0 + row) * 768 + k0 + cc * 8, &Bs[(w * 4 + iss) * 512]);
    }
    asm volatile("s_waitcnt vmcnt(0)" ::: "memory");
    __syncthreads();

#pragma unroll
    for (int ks = 0; ks < 2; ++ks) {
      bf16x8 af[4], bfr[4];
#pragma unroll
      for (int f = 0; f < 4; ++f) {
        int ar = wm * 64 + f * 16 + (lane & 15);
        int ac = (ks * 4 + (lane >> 4)) ^ (ar & 7);
        af[f] = *(const bf16x8*)&As[ar * 64 + ac * 8];
        int br = wn * 64 + f * 16 + (lane & 15);
        int bc = (ks * 4 + (lane >> 4)) ^ (br & 7);
        bfr[f] = *(const bf16x8*)&Bs[br * 64 + bc * 8];
      }
#pragma unroll
      for (int fm = 0; fm < 4; ++fm)
#pragma unroll
        for (int fn = 0; fn < 4; ++fn)
          acc[fm][fn] = __builtin_amdgcn_mfma_f32_16x16x32_bf16(af[fm], bfr[fn], acc[fm][fn], 0, 0, 0);
    }
    __syncthreads();
  }

  // epilogue: C row = r0+wm*64+fm*16+(lane>>4)*4+reg, col = c0+wn*64+fn*16+(lane&15)
  const int which = c0 / 768;  // tile never straddles (768 % 128 == 0)
#pragma unroll
  for (int fm = 0; fm < 4; ++fm) {
    int gr0 = r0 + wm * 64 + fm * 16 + ((lane >> 4) << 2);
    int bb = gr0 >> 11, n0 = gr0 & 2047;
#pragma unroll
    for (int fn = 0; fn < 4; ++fn) {
      int gc = c0 + wn * 64 + fn * 16 + (lane & 15);
      int rem = gc - which * 768;
      int h = rem >> 6, d = rem & 63;
      int bh = bb * HEADS + h;
      f32x4 v = acc[fm][fn];
      if (which == 2) {  // V stored transposed [bh][d][n]
        usx4 p;
        p[0] = f2bf(v[0]); p[1] = f2bf(v[1]); p[2] = f2bf(v[2]); p[3] = f2bf(v[3]);
        *(usx4*)&Vt[(size_t)(bh * 64 + d) * 2048 + n0] = p;
      } else {           // Q,K stored [bh][n][d]
        unsigned short* dst = (which == 0 ? Qb : Kb) + (size_t)(bh * 2048 + n0) * 64 + d;
        dst[0]   = f2bf(v[0]);
        dst[64]  = f2bf(v[1]);
        dst[128] = f2bf(v[2]);
        dst[192] = f2bf(v[3]);
      }
    }
  }
}

// ---------------- flash attention: 4 waves x 32 q-rows, KV tiles of 64 ----------------
__global__ __launch_bounds__(256) void k_attn(
    const unsigned short* __restrict__ Qb, const unsigned short* __restrict__ Kb,
    const unsigned short* __restrict__ Vt, unsigned short* __restrict__ Ob) {
  __shared__ unsigned short Ksm[64 * 64];
  __shared__ unsigned short Vsm[64 * 64];
  __shared__ unsigned short Psm[4][32][80];  // padded rows (160B) for aligned b128 reads
  const int lane = threadIdx.x & 63, w = threadIdx.x >> 6;
  const int bh = blockIdx.y;
  const int q0 = blockIdx.x * 128 + w * 32;
  const int bb = bh / HEADS, h = bh % HEADS;

  const unsigned short* Qp = Qb + (size_t)bh * SEQ * HD;
  const unsigned short* Kp = Kb + (size_t)bh * SEQ * HD;
  const unsigned short* Vp = Vt + (size_t)bh * HD * SEQ;

  bf16x8 aQ[2][2];
#pragma unroll
  for (int fm = 0; fm < 2; ++fm)
#pragma unroll
    for (int ks = 0; ks < 2; ++ks)
      aQ[fm][ks] = *(const bf16x8*)&Qp[(size_t)(q0 + fm * 16 + (lane & 15)) * 64 +
                                       ks * 32 + (lane >> 4) * 8];

  float mrun[2][4], lrun[2][4];
  f32x4 accO[2][4] = {};
#pragma unroll
  for (int fm = 0; fm < 2; ++fm)
#pragma unroll
    for (int r = 0; r < 4; ++r) { mrun[fm][r] = -1e30f; lrun[fm][r] = 0.f; }

  for (int kt = 0; kt < 32; ++kt) {
#pragma unroll
    for (int iss = 0; iss < 2; ++iss) {
      int eo = (w * 2 + iss) * 512 + lane * 8;
      int row = eo >> 6;
      int cc = ((eo >> 3) & 7) ^ (row & 7);
      gload_lds16(Kp + (size_t)(kt * 64 + row) * 64 + cc * 8, &Ksm[(w * 2 + iss) * 512]);
      gload_lds16(Vp + (size_t)row * 2048 + kt * 64 + cc * 8, &Vsm[(w * 2 + iss) * 512]);
    }
    asm volatile("s_waitcnt vmcnt(0)" ::: "memory");
    __syncthreads();

    // S = Q K^T  (raw, scale applied in softmax)
    f32x4 accS[2][4] = {};
#pragma unroll
    for (int ks = 0; ks < 2; ++ks) {
      bf16x8 bK[4];
#pragma unroll
      for (int fn = 0; fn < 4; ++fn) {
        int kr = fn * 16 + (lane & 15);
        int kc = (ks * 4 + (lane >> 4)) ^ (kr & 7);
        bK[fn] = *(const bf16x8*)&Ksm[kr * 64 + kc * 8];
      }
#pragma unroll
      for (int fm = 0; fm < 2; ++fm)
#pragma unroll
        for (int fn = 0; fn < 4; ++fn)
          accS[fm][fn] = __builtin_amdgcn_mfma_f32_16x16x32_bf16(aQ[fm][ks], bK[fn], accS[fm][fn], 0, 0, 0);
    }

    // online softmax; rows live on lanes sharing (lane>>4): reduce over lane&15
    float fac[2][4];
#pragma unroll
    for (int fm = 0; fm < 2; ++fm) {
#pragma unroll
      for (int r = 0; r < 4; ++r) {
        float mx = fmaxf(fmaxf(accS[fm][0][r], accS[fm][1][r]),
                         fmaxf(accS[fm][2][r], accS[fm][3][r]));
        mx = fmaxf(mx, __shfl_xor(mx, 1));
        mx = fmaxf(mx, __shfl_xor(mx, 2));
        mx = fmaxf(mx, __shfl_xor(mx, 4));
        mx = fmaxf(mx, __shfl_xor(mx, 8));
        float mn = fmaxf(mrun[fm][r], mx * QKV_SCALE);
        fac[fm][r] = __expf(mrun[fm][r] - mn);
        mrun[fm][r] = mn;
      }
      float rs[4] = {0.f, 0.f, 0.f, 0.f};
#pragma unroll
      for (int fn = 0; fn < 4; ++fn) {
        f32x4 sv = accS[fm][fn];
#pragma unroll
        for (int r = 0; r < 4; ++r) {
          float p = __expf(sv[r] * QKV_SCALE - mrun[fm][r]);
          rs[r] += p;
          Psm[w][fm * 16 + (lane >> 4) * 4 + r][fn * 16 + (lane & 15)] = f2bf(p);
        }
      }
#pragma unroll
      for (int r = 0; r < 4; ++r) {
        float t = rs[r];
        t += __shfl_xor(t, 1);
        t += __shfl_xor(t, 2);
        t += __shfl_xor(t, 4);
        t += __shfl_xor(t, 8);
        lrun[fm][r] = lrun[fm][r] * fac[fm][r] + t;
      }
#pragma unroll
      for (int fd = 0; fd < 4; ++fd) {
        f32x4 o = accO[fm][fd];
        o[0] *= fac[fm][0]; o[1] *= fac[fm][1]; o[2] *= fac[fm][2]; o[3] *= fac[fm][3];
        accO[fm][fd] = o;
      }
    }

    // O += P V   (P re-read from own-wave LDS as A-fragments; no barrier needed)
#pragma unroll
    for (int ks = 0; ks < 2; ++ks) {
      bf16x8 aP[2], bV[4];
#pragma unroll
      for (int fm = 0; fm < 2; ++fm)
        aP[fm] = *(const bf16x8*)&Psm[w][fm * 16 + (lane & 15)][ks * 32 + (lane >> 4) * 8];
#pragma unroll
      for (int fd = 0; fd < 4; ++fd) {
        int vr = fd * 16 + (lane & 15);
        int vc = (ks * 4 + (lane >> 4)) ^ (vr & 7);
        bV[fd] = *(const bf16x8*)&Vsm[vr * 64 + vc * 8];
      }
#pragma unroll
      for (int fm = 0; fm < 2; ++fm)
#pragma unroll
        for (int fd = 0; fd < 4; ++fd)
          accO[fm][fd] = __builtin_amdgcn_mfma_f32_16x16x32_bf16(aP[fm], bV[fd], accO[fm][fd], 0, 0, 0);
    }
    __syncthreads();
  }

#pragma unroll
  for (int fm = 0; fm < 2; ++fm) {
#pragma unroll
    for (int fd = 0; fd < 4; ++fd) {
      int d = fd * 16 + (lane & 15);
#pragma unroll
      for (int r = 0; r < 4; ++r) {
        int n = q0 + fm * 16 + (lane >> 4) * 4 + r;
        Ob[(size_t)(bb * SEQ + n) * CDIM + h * HD + d] = f2bf(accO[fm][fd][r] / lrun[fm][r]);
      }
    }
  }
}

// ---------------- proj GEMM: Ob[8192x768]bf16 @ WprojT + bias -> fp32 out ----------------
__global__ __launch_bounds__(256) void k_proj_gemm(
    const unsigned short* __restrict__ A,   // Ob [8192][768]
    const unsigned short* __restrict__ Bt,  // WprojT [768][768]
    const float* __restrict__ bias, float* __restrict__ out) {
  __shared__ unsigned short As[128 * 64];
  __shared__ unsigned short Bs[128 * 64];
  const int lane = threadIdx.x & 63, w = threadIdx.x >> 6;
  const int wm = w >> 1, wn = w & 1;
  const int r0 = blockIdx.y * 128, c0 = blockIdx.x * 128;
  f32x4 acc[4][4] = {};

  for (int k0 = 0; k0 < 768; k0 += 64) {
#pragma unroll
    for (int iss = 0; iss < 4; ++iss) {
      int eo = (w * 4 + iss) * 512 + lane * 8;
      int row = eo >> 6;
      int cc = ((eo >> 3) & 7) ^ (row & 7);
      gload_lds16(A + (size_t)(r0 + row) * 768 + k0 + cc * 8, &As[(w * 4 + iss) * 512]);
    }
#pragma unroll
    for (int iss = 0; iss < 4; ++iss) {
      int eo = (w * 4 + iss) * 512 + lane * 8;
      int row = eo >> 6;
      int cc = ((eo >> 3) & 7) ^ (row & 7);
      gload_lds16(Bt + (size_t)(c0 + row) * 768 + k0 + cc * 8, &Bs[(w * 4 + iss) * 512]);
    }
    asm volatile("s_waitcnt vmcnt(0)" ::: "memory");
    __syncthreads();

#pragma unroll
    for (int ks = 0; ks < 2; ++ks) {
      bf16x8 af[4], bfr[4];
#pragma unroll
      for (int f = 0; f < 4; ++f) {
        int ar = wm * 64 + f * 16 + (lane & 15);
        int ac = (ks * 4 + (lane >> 4)) ^ (ar & 7);
        af[f] = *(const bf16x8*)&As[ar * 64 + ac * 8];
        int br = wn * 64 + f * 16 + (lane & 15);
        int bc = (ks * 4 + (lane >> 4)) ^ (br & 7);
        bfr[f] = *(const bf16x8*)&Bs[br * 64 + bc * 8];
      }
#pragma unroll
      for (int fm = 0; fm < 4; ++fm)
#pragma unroll
        for (int fn = 0; fn < 4; ++fn)
          acc[fm][fn] = __builtin_amdgcn_mfma_f32_16x16x32_bf16(af[fm], bfr[fn], acc[fm][fn], 0, 0, 0);
    }
    __syncthreads();
  }

#pragma unroll
  for (int fm = 0; fm < 4; ++fm) {
    int gr0 = r0 + wm * 64 + fm * 16 + ((lane >> 4) << 2);
#pragma unroll
    for (int fn = 0; fn < 4; ++fn) {
      int gc = c0 + wn * 64 + fn * 16 + (lane & 15);
      float bsv = bias[gc];
      f32x4 v = acc[fm][fn];
#pragma unroll
      for (int r = 0; r < 4; ++r)
        out[(size_t)(gr0 + r) * CDIM + gc] = v[r] + bsv;
    }
  }
}

extern "C" void kernel_launch(void* const* d_in, const int* in_sizes, int n_in,
                              void* d_out, int out_size, void* d_ws, size_t ws_size,
                              hipStream_t stream) {
  const float* x      = (const float*)d_in[0];
  const float* W_qkv  = (const float*)d_in[1];
  const float* W_proj = (const float*)d_in[2];
  const float* b_proj = (const float*)d_in[3];
  float* out = (float*)d_out;

  unsigned short* ws     = (unsigned short*)d_ws;
  unsigned short* xb     = ws;                   // 8192*768
  unsigned short* WqkvT  = xb + 6291456;         // 2304*768
  unsigned short* WprojT = WqkvT + 1769472;      // 768*768
  unsigned short* Qb     = WprojT + 589824;      // 48*2048*64
  unsigned short* Kb     = Qb + 6291456;
  unsigned short* Vt     = Kb + 6291456;         // transposed [48][64][2048]
  unsigned short* Ob     = Vt + 6291456;         // 8192*768
  // total: 33,816,576 bf16 = ~67.6 MB of d_ws

  k_cvt_x<<<3072, 256, 0, stream>>>(x, xb);
  k_transpose<<<dim3(72, 24), 256, 0, stream>>>(W_qkv, WqkvT, 768, 2304);
  k_transpose<<<dim3(24, 24), 256, 0, stream>>>(W_proj, WprojT, 768, 768);
  k_qkv_gemm<<<dim3(18, 64), 256, 0, stream>>>(xb, WqkvT, Qb, Kb, Vt);
  k_attn<<<dim3(16, 48), 256, 0, stream>>>(Qb, Kb, Vt, Ob);
  k_proj_gemm<<<dim3(6, 64), 256, 0, stream>>>(Ob, WprojT, b_proj, out);
}

// Round 2
// 164.767 us; speedup vs baseline: 1.4628x; 1.4628x over previous
//
#include <hip/hip_runtime.h>
#include <hip/hip_bf16.h>

#define HEADS 12
#define HD    64
#define SEQ   2048
#define CDIM  768
#define QKV_SCALE 0.03608439182435161f  // 768^-0.5 (module scales by full dim)
#define LOG2E 1.4426950408889634f
#define SM_C (QKV_SCALE * LOG2E)        // p = 2^(s*SM_C - m2)

typedef __attribute__((ext_vector_type(8))) short bf16x8;
typedef __attribute__((ext_vector_type(4))) float f32x4;
typedef __attribute__((ext_vector_type(4))) unsigned short usx4;
typedef __attribute__((ext_vector_type(8))) unsigned short usx8;
typedef __attribute__((ext_vector_type(2))) unsigned int uix2;
typedef __attribute__((ext_vector_type(4))) unsigned int uix4;

__device__ __forceinline__ unsigned short f2bf(float f) {
  union { __hip_bfloat16 h; unsigned short u; } c;
  c.h = __float2bfloat16(f);
  return c.u;
}

__device__ __forceinline__ float exp2_fast(float x) {
  float r; asm("v_exp_f32 %0, %1" : "=v"(r) : "v"(x)); return r;
}

__device__ __forceinline__ unsigned int cvt_pk_bf16(float lo, float hi) {
  unsigned int r; asm("v_cvt_pk_bf16_f32 %0, %1, %2" : "=v"(r) : "v"(lo), "v"(hi)); return r;
}

__device__ __forceinline__ void gload_lds16(const unsigned short* g, unsigned short* l) {
  __builtin_amdgcn_global_load_lds(
      (__attribute__((address_space(1))) void*)(g),
      (__attribute__((address_space(3))) void*)(l), 16, 0, 0);
}

// ---------------- convert x (fp32 -> bf16), 8 elems/thread ----------------
__global__ __launch_bounds__(256) void k_cvt_x(const float* __restrict__ src,
                                               unsigned short* __restrict__ dst) {
  int i = blockIdx.x * 256 + threadIdx.x;
  const float4* s4 = (const float4*)src;
  float4 a = s4[i * 2 + 0];
  float4 b = s4[i * 2 + 1];
  usx8 r;
  r[0] = f2bf(a.x); r[1] = f2bf(a.y); r[2] = f2bf(a.z); r[3] = f2bf(a.w);
  r[4] = f2bf(b.x); r[5] = f2bf(b.y); r[6] = f2bf(b.z); r[7] = f2bf(b.w);
  *(usx8*)&dst[i * 8] = r;
}

// ---------------- transpose fp32 [K][C] -> bf16 [C][K] ----------------
__global__ __launch_bounds__(256) void k_transpose(const float* __restrict__ src,
                                                   unsigned short* __restrict__ dst,
                                                   int K, int C) {
  __shared__ float tile[32][33];
  int tx = threadIdx.x & 31;
  int ty = threadIdx.x >> 5;
  int c0 = blockIdx.x * 32;
  int k0 = blockIdx.y * 32;
#pragma unroll
  for (int i = 0; i < 32; i += 8)
    tile[ty + i][tx] = src[(size_t)(k0 + ty + i) * C + c0 + tx];
  __syncthreads();
#pragma unroll
  for (int i = 0; i < 32; i += 8)
    dst[(size_t)(c0 + ty + i) * K + k0 + tx] = f2bf(tile[tx][ty + i]);
}

// ---------------- qkv GEMM: [8192x768]bf16 @ [768x2304] -> scatter Q,K,V^T ----------------
__global__ __launch_bounds__(256) void k_qkv_gemm(
    const unsigned short* __restrict__ A,   // xb [8192][768]
    const unsigned short* __restrict__ Bt,  // WqkvT [2304][768]
    unsigned short* __restrict__ Qb, unsigned short* __restrict__ Kb,
    unsigned short* __restrict__ Vt) {
  __shared__ unsigned short As[128 * 64];
  __shared__ unsigned short Bs[128 * 64];
  const int lane = threadIdx.x & 63, w = threadIdx.x >> 6;
  const int wm = w >> 1, wn = w & 1;
  const int r0 = blockIdx.y * 128, c0 = blockIdx.x * 128;
  f32x4 acc[4][4] = {};

  for (int k0 = 0; k0 < 768; k0 += 64) {
#pragma unroll
    for (int iss = 0; iss < 4; ++iss) {
      int eo = (w * 4 + iss) * 512 + lane * 8;
      int row = eo >> 6;
      int cc = ((eo >> 3) & 7) ^ (row & 7);
      gload_lds16(A + (size_t)(r0 + row) * 768 + k0 + cc * 8, &As[(w * 4 + iss) * 512]);
    }
#pragma unroll
    for (int iss = 0; iss < 4; ++iss) {
      int eo = (w * 4 + iss) * 512 + lane * 8;
      int row = eo >> 6;
      int cc = ((eo >> 3) & 7) ^ (row & 7);
      gload_lds16(Bt + (size_t)(c0 + row) * 768 + k0 + cc * 8, &Bs[(w * 4 + iss) * 512]);
    }
    asm volatile("s_waitcnt vmcnt(0)" ::: "memory");
    __syncthreads();

#pragma unroll
    for (int ks = 0; ks < 2; ++ks) {
      bf16x8 af[4], bfr[4];
#pragma unroll
      for (int f = 0; f < 4; ++f) {
        int ar = wm * 64 + f * 16 + (lane & 15);
        int ac = (ks * 4 + (lane >> 4)) ^ (ar & 7);
        af[f] = *(const bf16x8*)&As[ar * 64 + ac * 8];
        int br = wn * 64 + f * 16 + (lane & 15);
        int bc = (ks * 4 + (lane >> 4)) ^ (br & 7);
        bfr[f] = *(const bf16x8*)&Bs[br * 64 + bc * 8];
      }
#pragma unroll
      for (int fm = 0; fm < 4; ++fm)
#pragma unroll
        for (int fn = 0; fn < 4; ++fn)
          acc[fm][fn] = __builtin_amdgcn_mfma_f32_16x16x32_bf16(af[fm], bfr[fn], acc[fm][fn], 0, 0, 0);
    }
    __syncthreads();
  }

  const int which = c0 / 768;
#pragma unroll
  for (int fm = 0; fm < 4; ++fm) {
    int gr0 = r0 + wm * 64 + fm * 16 + ((lane >> 4) << 2);
    int bb = gr0 >> 11, n0 = gr0 & 2047;
#pragma unroll
    for (int fn = 0; fn < 4; ++fn) {
      int gc = c0 + wn * 64 + fn * 16 + (lane & 15);
      int rem = gc - which * 768;
      int h = rem >> 6, d = rem & 63;
      int bh = bb * HEADS + h;
      f32x4 v = acc[fm][fn];
      if (which == 2) {
        usx4 p;
        p[0] = f2bf(v[0]); p[1] = f2bf(v[1]); p[2] = f2bf(v[2]); p[3] = f2bf(v[3]);
        *(usx4*)&Vt[(size_t)(bh * 64 + d) * 2048 + n0] = p;
      } else {
        unsigned short* dst = (which == 0 ? Qb : Kb) + (size_t)(bh * 2048 + n0) * 64 + d;
        dst[0]   = f2bf(v[0]);
        dst[64]  = f2bf(v[1]);
        dst[128] = f2bf(v[2]);
        dst[192] = f2bf(v[3]);
      }
    }
  }
}

// ---------------- flash attention: swapped-QK in-register softmax, 2-phase dbuf ----------------
__global__ __launch_bounds__(256, 2) void k_attn(
    const unsigned short* __restrict__ Qb, const unsigned short* __restrict__ Kb,
    const unsigned short* __restrict__ Vt, unsigned short* __restrict__ Ob) {
  __shared__ unsigned short Ksm[2][64 * 64];
  __shared__ unsigned short Vsm[2][64 * 64];
  const int lane = threadIdx.x & 63, w = threadIdx.x >> 6;
  const int g = lane >> 4, c = lane & 15;

  // XCD-aware swizzle: 768 blocks -> each XCD owns 96 consecutive logical tiles (6 heads of K/V)
  int id = blockIdx.x + (blockIdx.y << 4);
  int lin = (id & 7) * 96 + (id >> 3);
  int bx = lin & 15, bh = lin >> 4;
  const int q0 = bx * 128 + w * 32;
  const int bb = bh / HEADS, h = bh % HEADS;

  const unsigned short* Qp = Qb + (size_t)bh * SEQ * HD;
  const unsigned short* Kp = Kb + (size_t)bh * SEQ * HD;
  const unsigned short* Vp = Vt + (size_t)bh * HD * SEQ;

  // Q as B-fragment (S^T = K * Q^T): lane holds q-col = c, d = ks*32 + g*8 + j
  bf16x8 aQ[2][2];
#pragma unroll
  for (int qf = 0; qf < 2; ++qf)
#pragma unroll
    for (int ks = 0; ks < 2; ++ks)
      aQ[qf][ks] = *(const bf16x8*)&Qp[(size_t)(q0 + qf * 16 + c) * 64 + ks * 32 + g * 8];

  float mrun[2] = {-1e30f, -1e30f}, lrun[2] = {0.f, 0.f};
  f32x4 accOT[4][2] = {};  // O^T fragments: [fd][qf]; lane: q=c, d=fd*16+4g+r

  auto STAGE = [&](int kt, int b) {
#pragma unroll
    for (int iss = 0; iss < 2; ++iss) {
      int eo = (w * 2 + iss) * 512 + lane * 8;
      int row = eo >> 6;
      int cc = ((eo >> 3) & 7) ^ (row & 7);
      gload_lds16(Kp + (size_t)(kt * 64 + row) * 64 + cc * 8, &Ksm[b][(w * 2 + iss) * 512]);
      gload_lds16(Vp + (size_t)row * 2048 + kt * 64 + cc * 8, &Vsm[b][(w * 2 + iss) * 512]);
    }
  };

  STAGE(0, 0);
  asm volatile("s_waitcnt vmcnt(0)" ::: "memory");
  __syncthreads();
  int buf = 0;

  for (int kt = 0; kt < 32; ++kt) {
    if (kt + 1 < 32) STAGE(kt + 1, buf ^ 1);  // prefetch hides under compute

    // S^T = K Q^T : accST[fm][qf], lane: key = fm*16 + 4g + r, q = c
    f32x4 accST[4][2] = {};
    __builtin_amdgcn_s_setprio(1);
#pragma unroll
    for (int ks = 0; ks < 2; ++ks) {
      bf16x8 kf[4];
#pragma unroll
      for (int fm = 0; fm < 4; ++fm) {
        int row = fm * 16 + c;
        kf[fm] = *(const bf16x8*)&Ksm[buf][row * 64 + (((ks * 4 + g) ^ (row & 7)) * 8)];
      }
#pragma unroll
      for (int fm = 0; fm < 4; ++fm)
#pragma unroll
        for (int qf = 0; qf < 2; ++qf)
          accST[fm][qf] = __builtin_amdgcn_mfma_f32_16x16x32_bf16(kf[fm], aQ[qf][ks], accST[fm][qf], 0, 0, 0);
    }
    __builtin_amdgcn_s_setprio(0);

    // in-register online softmax (per q-column, lane-local 16 keys + 2 shuffles)
    uix4 pfrag[2][2];  // B-fragment of P^T: [ks][qf]
#pragma unroll
    for (int qf = 0; qf < 2; ++qf) {
      float mx = fmaxf(fmaxf(accST[0][qf][0], accST[0][qf][1]),
                       fmaxf(accST[0][qf][2], accST[0][qf][3]));
#pragma unroll
      for (int fm = 1; fm < 4; ++fm)
        mx = fmaxf(mx, fmaxf(fmaxf(accST[fm][qf][0], accST[fm][qf][1]),
                             fmaxf(accST[fm][qf][2], accST[fm][qf][3])));
      mx = fmaxf(mx, __shfl_xor(mx, 16));
      mx = fmaxf(mx, __shfl_xor(mx, 32));
      float mx2 = mx * SM_C;

      if (!__all(mx2 <= mrun[qf] + 8.0f)) {  // defer-max (T13)
        float mnew = fmaxf(mrun[qf], mx2);
        float fac = exp2_fast(mrun[qf] - mnew);
        mrun[qf] = mnew;
        lrun[qf] *= fac;
#pragma unroll
        for (int fd = 0; fd < 4; ++fd) {
          f32x4 o = accOT[fd][qf];
          o[0] *= fac; o[1] *= fac; o[2] *= fac; o[3] *= fac;
          accOT[fd][qf] = o;
        }
      }

      float p[4][4];
      float ssum = 0.f;
#pragma unroll
      for (int fm = 0; fm < 4; ++fm)
#pragma unroll
        for (int r = 0; r < 4; ++r) {
          float pv = exp2_fast(fmaf(accST[fm][qf][r], SM_C, -mrun[qf]));
          p[fm][r] = pv;
          ssum += pv;
        }
      ssum += __shfl_xor(ssum, 16);
      ssum += __shfl_xor(ssum, 32);
      lrun[qf] += ssum;

      // C-frag (4-granular) -> B-frag (8-granular): cvt_pk + permlane32 + permlane16
#pragma unroll
      for (int ks = 0; ks < 2; ++ks)
#pragma unroll
        for (int t = 0; t < 2; ++t) {
          unsigned int a = cvt_pk_bf16(p[2 * ks][2 * t], p[2 * ks][2 * t + 1]);
          unsigned int b = cvt_pk_bf16(p[2 * ks + 1][2 * t], p[2 * ks + 1][2 * t + 1]);
          uix2 s1 = __builtin_amdgcn_permlane32_swap(a, b, false, false);
          uix2 s2 = __builtin_amdgcn_permlane16_swap(s1[0], s1[1], false, false);
          pfrag[ks][qf][t] = s2[0];      // keys 8g+2t, 8g+2t+1
          pfrag[ks][qf][2 + t] = s2[1];  // keys 8g+4+2t, 8g+4+2t+1
        }
    }

    // O^T += V^T P^T
    __builtin_amdgcn_s_setprio(1);
#pragma unroll
    for (int ks = 0; ks < 2; ++ks) {
      bf16x8 vf[4];
#pragma unroll
      for (int fd = 0; fd < 4; ++fd) {
        int row = fd * 16 + c;
        vf[fd] = *(const bf16x8*)&Vsm[buf][row * 64 + (((ks * 4 + g) ^ (row & 7)) * 8)];
      }
#pragma unroll
      for (int fd = 0; fd < 4; ++fd)
#pragma unroll
        for (int qf = 0; qf < 2; ++qf)
          accOT[fd][qf] = __builtin_amdgcn_mfma_f32_16x16x32_bf16(
              vf[fd], *(const bf16x8*)&pfrag[ks][qf], accOT[fd][qf], 0, 0, 0);
    }
    __builtin_amdgcn_s_setprio(0);

    asm volatile("s_waitcnt vmcnt(0)" ::: "memory");
    __syncthreads();
    buf ^= 1;
  }

  // epilogue: lane holds q=c, d=fd*16+4g+r -> packed 8B stores
#pragma unroll
  for (int qf = 0; qf < 2; ++qf) {
    float rl = 1.0f / lrun[qf];
    int n = q0 + qf * 16 + c;
#pragma unroll
    for (int fd = 0; fd < 4; ++fd) {
      f32x4 v = accOT[fd][qf];
      usx4 pk;
      pk[0] = f2bf(v[0] * rl); pk[1] = f2bf(v[1] * rl);
      pk[2] = f2bf(v[2] * rl); pk[3] = f2bf(v[3] * rl);
      *(usx4*)&Ob[(size_t)(bb * SEQ + n) * CDIM + h * HD + fd * 16 + 4 * g] = pk;
    }
  }
}

// ---------------- proj GEMM: Ob[8192x768]bf16 @ WprojT + bias -> fp32 out ----------------
__global__ __launch_bounds__(256) void k_proj_gemm(
    const unsigned short* __restrict__ A,   // Ob [8192][768]
    const unsigned short* __restrict__ Bt,  // WprojT [768][768]
    const float* __restrict__ bias, float* __restrict__ out) {
  __shared__ unsigned short As[128 * 64];
  __shared__ unsigned short Bs[128 * 64];
  const int lane = threadIdx.x & 63, w = threadIdx.x >> 6;
  const int wm = w >> 1, wn = w & 1;
  const int r0 = blockIdx.y * 128, c0 = blockIdx.x * 128;
  f32x4 acc[4][4] = {};

  for (int k0 = 0; k0 < 768; k0 += 64) {
#pragma unroll
    for (int iss = 0; iss < 4; ++iss) {
      int eo = (w * 4 + iss) * 512 + lane * 8;
      int row = eo >> 6;
      int cc = ((eo >> 3) & 7) ^ (row & 7);
      gload_lds16(A + (size_t)(r0 + row) * 768 + k0 + cc * 8, &As[(w * 4 + iss) * 512]);
    }
#pragma unroll
    for (int iss = 0; iss < 4; ++iss) {
      int eo = (w * 4 + iss) * 512 + lane * 8;
      int row = eo >> 6;
      int cc = ((eo >> 3) & 7) ^ (row & 7);
      gload_lds16(Bt + (size_t)(c0 + row) * 768 + k0 + cc * 8, &Bs[(w * 4 + iss) * 512]);
    }
    asm volatile("s_waitcnt vmcnt(0)" ::: "memory");
    __syncthreads();

#pragma unroll
    for (int ks = 0; ks < 2; ++ks) {
      bf16x8 af[4], bfr[4];
#pragma unroll
      for (int f = 0; f < 4; ++f) {
        int ar = wm * 64 + f * 16 + (lane & 15);
        int ac = (ks * 4 + (lane >> 4)) ^ (ar & 7);
        af[f] = *(const bf16x8*)&As[ar * 64 + ac * 8];
        int br = wn * 64 + f * 16 + (lane & 15);
        int bc = (ks * 4 + (lane >> 4)) ^ (br & 7);
        bfr[f] = *(const bf16x8*)&Bs[br * 64 + bc * 8];
      }
#pragma unroll
      for (int fm = 0; fm < 4; ++fm)
#pragma unroll
        for (int fn = 0; fn < 4; ++fn)
          acc[fm][fn] = __builtin_amdgcn_mfma_f32_16x16x32_bf16(af[fm], bfr[fn], acc[fm][fn], 0, 0, 0);
    }
    __syncthreads();
  }

#pragma unroll
  for (int fm = 0; fm < 4; ++fm) {
    int gr0 = r0 + wm * 64 + fm * 16 + ((lane >> 4) << 2);
#pragma unroll
    for (int fn = 0; fn < 4; ++fn) {
      int gc = c0 + wn * 64 + fn * 16 + (lane & 15);
      float bsv = bias[gc];
      f32x4 v = acc[fm][fn];
#pragma unroll
      for (int r = 0; r < 4; ++r)
        out[(size_t)(gr0 + r) * CDIM + gc] = v[r] + bsv;
    }
  }
}

extern "C" void kernel_launch(void* const* d_in, const int* in_sizes, int n_in,
                              void* d_out, int out_size, void* d_ws, size_t ws_size,
                              hipStream_t stream) {
  const float* x      = (const float*)d_in[0];
  const float* W_qkv  = (const float*)d_in[1];
  const float* W_proj = (const float*)d_in[2];
  const float* b_proj = (const float*)d_in[3];
  float* out = (float*)d_out;

  unsigned short* ws     = (unsigned short*)d_ws;
  unsigned short* xb     = ws;                   // 8192*768
  unsigned short* WqkvT  = xb + 6291456;         // 2304*768
  unsigned short* WprojT = WqkvT + 1769472;      // 768*768
  unsigned short* Qb     = WprojT + 589824;      // 48*2048*64
  unsigned short* Kb     = Qb + 6291456;
  unsigned short* Vt     = Kb + 6291456;         // transposed [48][64][2048]
  unsigned short* Ob     = Vt + 6291456;         // 8192*768

  k_cvt_x<<<3072, 256, 0, stream>>>(x, xb);
  k_transpose<<<dim3(72, 24), 256, 0, stream>>>(W_qkv, WqkvT, 768, 2304);
  k_transpose<<<dim3(24, 24), 256, 0, stream>>>(W_proj, WprojT, 768, 768);
  k_qkv_gemm<<<dim3(18, 64), 256, 0, stream>>>(xb, WqkvT, Qb, Kb, Vt);
  k_attn<<<dim3(16, 48), 256, 0, stream>>>(Qb, Kb, Vt, Ob);
  k_proj_gemm<<<dim3(6, 64), 256, 0, stream>>>(Ob, WprojT, b_proj, out);
}